// Round 19
// baseline (391.332 us; speedup 1.0000x reference)
//
#include <hip/hip_runtime.h>
#include <hip/hip_bf16.h>
#include <math.h>

#define LSN 2
#define BSN 16
#define NH 256
#define NP 512
#define MIDP 256
#define TTN 16
#define DIN 64
#define NCH 4096
#define GW 1024
#define PRS 268   // prstage LDS row stride (floats)
#define BUFSZ 36864  // one double-buffer slot: A[128][72] + B[128][72] f16

typedef _Float16 f16;
typedef _Float16 f16x8 __attribute__((ext_vector_type(8)));
typedef float f32x4 __attribute__((ext_vector_type(4)));

// r5-proven activation numerics (libm expf/tanhf). DO NOT replace with __expf:
// fp16-amplified activation noise flips resample argsort near-ties (r6-r8).
__device__ __forceinline__ float fsig(float x){ return 1.0f/(1.0f+expf(-x)); }

__device__ __forceinline__ float brsum512(float v, float* red){
  int tid = threadIdx.x;
  red[tid]=v; __syncthreads();
  for (int s=256; s>0; s>>=1){ if (tid<s) red[tid]+=red[tid+s]; __syncthreads(); }
  float r = red[0]; __syncthreads(); return r;
}

// gate-row remap: jhat = y*128 + q*32 + m  <->  source row = q*256 + y*32 + m
__device__ __forceinline__ int gsrow(int jp){
  return ((jp>>5)&3)*NH + (jp>>7)*32 + (jp&31);
}

// ---------- fused prep: [0,1024) weights, [1024,1280) xW0, [1280,1792) init ----------
__global__ __launch_bounds__(256) void k_prep_all(
    const float* __restrict__ Whh0, const float* __restrict__ Wih1,
    const float* __restrict__ Whh1, const float* __restrict__ b1,
    const float* __restrict__ x, const float* __restrict__ Wih0,
    const float* __restrict__ b0, const float* __restrict__ part,
    f16* __restrict__ W0i, f16* __restrict__ W1c, float* __restrict__ b1i,
    float* __restrict__ xW0,
    f16* __restrict__ h0, f16* __restrict__ h1,
    float* __restrict__ c0, float* __restrict__ c1)
{
  __shared__ float lh[64][65];
  __shared__ float lcv[64][65];
  int bid = blockIdx.x;
  int tid = threadIdx.x;
  if (bid < 1024){
    int jp = bid; int srow = gsrow(jp); int t = tid;
    W0i[(size_t)jp*NH + t]        = (f16)Whh0[(size_t)srow*NH + t];
    W1c[(size_t)jp*512 + t]       = (f16)Wih1[(size_t)srow*NH + t];
    W1c[(size_t)jp*512 + 256 + t] = (f16)Whh1[(size_t)srow*NH + t];
    if (t==0) b1i[jp] = b1[srow];
  } else if (bid < 1280){
    int row = bid - 1024; // b*16+t
    float* xr = lh[0];
    if (tid < DIN) xr[tid] = x[(size_t)row*DIN + tid];
    __syncthreads();
    int n = tid;
    for (int q=0;q<4;++q){
      int wrow = q*NH + n;
      float acc = b0[wrow];
      #pragma unroll 8
      for (int d=0; d<DIN; ++d) acc += xr[d] * Wih0[(size_t)wrow*DIN + d];
      int jhat = (n>>5)*128 + q*32 + (n&31);
      xW0[(size_t)row*GW + jhat] = acc;
    }
  } else {
    int idx = bid - 1280;          // [0,512)
    int xb = idx & 15, b = (idx>>4)&15, l = idx>>8;
    int i0 = (xb >> 2)*64, n0 = (xb & 3)*64;
    #pragma unroll
    for (int rep=0; rep<16; ++rep){
      int nn = rep*4 + (tid>>6);
      int ii = tid & 63;
      size_t rowb = ((size_t)(l*BSN + b)*NH + n0 + nn)*NP;
      lh[nn][ii]  = part[rowb + i0 + ii];
      lcv[nn][ii] = part[rowb + MIDP + i0 + ii];
    }
    __syncthreads();
    f16* h = l ? h1 : h0;
    float* c = l ? c1 : c0;
    #pragma unroll
    for (int rep=0; rep<16; ++rep){
      int ii = rep*4 + (tid>>6);
      int nn = tid & 63;
      size_t chain = (size_t)b*256 + i0 + ii;
      h[chain*NH + n0 + nn] = (f16)lh[nn][ii];
      c[chain*NH + n0 + nn] = lcv[nn][ii];
    }
  }
}

// ---------- fused step, XCD-affine 1D grid ----------
struct StepCfg {
  const f16* A1; const f16* A2;
  float* C; f16* Hout;
  int layer; int t; int is_last;
};

__global__ __launch_bounds__(256) void k_step2(
    StepCfg cfgA, StepCfg cfgB,
    const f16* __restrict__ W0i, const f16* __restrict__ W1c,
    const float* __restrict__ xw0, const float* __restrict__ b1i,
    float* __restrict__ pr, const float* __restrict__ eps_h, const float* __restrict__ eps_c,
    const float* __restrict__ qp, const float* __restrict__ ep)
{
  __shared__ __align__(16) char smem[2*BUFSZ];   // 72 KB double buffer

  const int bid = blockIdx.x;
  const int xcd = bid & 7, jj = bid >> 3;
  const int mloc = jj & 3, y = (jj >> 2) & 7, z = (jj >> 5) & 1;
  const int mt = xcd*4 + mloc;         // m-tile 0..31
  const int m0 = mt * 128;

  const StepCfg cfg = z ? cfgB : cfgA;
  const int layer  = cfg.layer;
  const int Kt     = layer ? 512 : 256;
  const int nslice = layer ? 8 : 4;
  const f16* W     = layer ? W1c : W0i;

  const int tid = threadIdx.x;
  const int lane = tid & 63, wid = tid >> 6;
  const int lr = lane >> 4, lc = lane & 15;
  const int wm = wid * 32;
  const int bb = mt >> 1;              // chain = b*256+i -> b uniform per block

  float cold[2][2][4];
  #pragma unroll
  for (int mi=0; mi<2; ++mi)
    #pragma unroll
    for (int mh=0; mh<2; ++mh)
      #pragma unroll
      for (int r=0; r<4; ++r)
        cold[mi][mh][r] = cfg.C[(size_t)(m0 + wm + mi*16 + lr*4 + r)*NH + y*32 + mh*16 + lc];

  f32x4 acc[2][8];
  #pragma unroll
  for (int mi=0;mi<2;++mi)
    #pragma unroll
    for (int ni=0;ni<8;++ni) acc[mi][ni] = (f32x4){0.f,0.f,0.f,0.f};

  const int srow = tid >> 1, sseg = (tid & 1)*32;

  float4 ra0,ra1,ra2,ra3, rb0,rb1,rb2,rb3;
  auto loadslice = [&](int ks){
    const f16* Ab; int ka;
    if (layer==1 && ks>=4){ Ab = cfg.A2; ka = (ks-4)*64; } else { Ab = cfg.A1; ka = ks*64; }
    const float4* sa = (const float4*)(Ab + (size_t)(m0+srow)*NH + ka + sseg);
    const float4* sb = (const float4*)(W + (size_t)(y*128+srow)*Kt + (size_t)ks*64 + sseg);
    ra0=sa[0]; ra1=sa[1]; ra2=sa[2]; ra3=sa[3];
    rb0=sb[0]; rb1=sb[1]; rb2=sb[2]; rb3=sb[3];
  };
  auto writeslice = [&](int buf){
    f16* base = (f16*)(smem + buf*BUFSZ);
    float4* da = (float4*)(base + srow*72 + sseg);
    da[0]=ra0; da[1]=ra1; da[2]=ra2; da[3]=ra3;
    float4* db = (float4*)(base + 128*72 + srow*72 + sseg);
    db[0]=rb0; db[1]=rb1; db[2]=rb2; db[3]=rb3;
  };

  loadslice(0);
  writeslice(0);
  __syncthreads();
  for (int ks=0; ks<nslice; ++ks){
    const int cur = ks & 1;
    const bool more = (ks+1) < nslice;
    if (more) loadslice(ks+1);
    const f16* bufA = (const f16*)(smem + cur*BUFSZ);
    const f16* bufB = bufA + 128*72;
    #pragma unroll
    for (int k2=0;k2<2;++k2){
      const int koff = k2*32 + lr*8;
      f16x8 a0 = *(const f16x8*)(bufA + (wm +  0 + lc)*72 + koff);
      f16x8 a1 = *(const f16x8*)(bufA + (wm + 16 + lc)*72 + koff);
      f16x8 b[8];
      #pragma unroll
      for (int ni=0;ni<8;++ni) b[ni] = *(const f16x8*)(bufB + (ni*16 + lc)*72 + koff);
      #pragma unroll
      for (int ni=0;ni<8;++ni){
        acc[0][ni] = __builtin_amdgcn_mfma_f32_16x16x32_f16(a0, b[ni], acc[0][ni], 0,0,0);
        acc[1][ni] = __builtin_amdgcn_mfma_f32_16x16x32_f16(a1, b[ni], acc[1][ni], 0,0,0);
      }
    }
    if (more) writeslice(cur ^ 1);
    __syncthreads();
  }

  float addv[4][2];
  {
    const float* ar = (layer==0) ? (xw0 + (size_t)(bb*TTN + cfg.t)*GW + y*128)
                                 : (b1i + y*128);
    #pragma unroll
    for (int q=0;q<4;++q)
      #pragma unroll
      for (int mh=0;mh<2;++mh)
        addv[q][mh] = ar[q*32 + mh*16 + lc];
  }

  float sq=0.f, se=0.f;
  float* prstage = (float*)smem;
  if (cfg.is_last){
    sq = sqrtf(qp[0]*qp[0]); se = sqrtf(ep[0]*ep[0]);
  }

  #pragma unroll
  for (int mi=0;mi<2;++mi)
   #pragma unroll
   for (int mh=0;mh<2;++mh)
    #pragma unroll
    for (int r=0;r<4;++r){
      float gi = acc[mi][mh+0][r] + addv[0][mh];
      float gf = acc[mi][mh+2][r] + addv[1][mh];
      float gg = acc[mi][mh+4][r] + addv[2][mh];
      float go = acc[mi][mh+6][r] + addv[3][mh];
      float c2 = fsig(gf)*cold[mi][mh][r] + fsig(gi)*tanhf(gg);
      float h2 = fsig(go)*tanhf(c2);
      int ml = wm + mi*16 + lr*4 + r;
      int chain = m0 + ml;
      int nglob = y*32 + mh*16 + lc;
      cfg.Hout[(size_t)chain*NH + nglob] = (f16)h2;
      if (!cfg.is_last){
        cfg.C[(size_t)chain*NH + nglob] = c2;
      } else {
        int ip = (mt & 1)*128 + ml;
        size_t eidx = ((size_t)(ip*LSN + layer)*BSN + bb)*NH + nglob;
        int nl = mh*16 + lc;
        prstage[nl*PRS + ml]       = h2 + sq*eps_h[eidx];
        prstage[nl*PRS + 128 + ml] = c2 + se*eps_c[eidx];
      }
    }

  if (cfg.is_last){
    __syncthreads();
    #pragma unroll
    for (int s=0;s<8;++s){
      int u = s*256 + tid;
      int nl = u >> 6, within = u & 63;
      int half = within >> 5, q4 = within & 31;
      size_t rowp = (size_t)(layer*BSN + bb)*NH + y*32 + nl;
      float4 v = *(const float4*)(prstage + nl*PRS + half*128 + q4*4);
      *(float4*)(pr + rowp*NP + half*MIDP + (mt & 1)*128 + q4*4) = v;
    }
  }
}

// ---------- post kernels ----------
__global__ void k_obs_stats(const float* __restrict__ pr, const float* __restrict__ Wh,
                            const float* __restrict__ bh, const float* __restrict__ wts,
                            const float* __restrict__ yv, const float* __restrict__ rp,
                            float* __restrict__ Y, float* __restrict__ pre){
  int b = blockIdx.x; int N = threadIdx.x;   // 512 threads
  __shared__ float red[512];
  float acc = bh[0];
  for (int n=0;n<NH;++n) acc += Wh[n] * pr[((size_t)(BSN + b)*NH + n)*NP + N];
  Y[(size_t)b*NP + N] = acc;
  float lw = logf(wts[b*NP+N]);
  float SW = brsum512(lw, red);
  float SY = brsum512(acc*lw, red);
  float mu = SY/SW;
  float cen = acc-mu;
  float SC = brsum512(cen*cen, red);
  float sig = SC/511.0f + rp[0]*rp[0];
  float a = sig+1e-6f, inv = 1.0f/a, ld = logf(a);
  float i0 = yv[b] - acc*lw/SW;
  pre[b*NP+N] = lw - 0.5f*ld - 0.5f*inv*i0*i0;
}

// resample (+ colsoftmax, per-half trees bitwise == r18) + Yf/wf in LDS + final_est
// grid: 16 blocks x 512 threads; block b owns both halves of batch b.
__global__ void k_resample_final(const float* __restrict__ pre, const float* __restrict__ gum,
                                 const float* __restrict__ Y, const float* __restrict__ yv,
                                 const float* __restrict__ rp,
                                 int* __restrict__ idxb, int* __restrict__ dofl,
                                 float* __restrict__ qf, float* __restrict__ ldb,
                                 float* __restrict__ out){
  int b = blockIdx.x;
  int tid = threadIdx.x;            // 0..511
  int hf = tid >> 8, j = tid & 255;
  int N = tid;                      // hf*256 + j
  __shared__ float red[512];
  __shared__ float key[512];
  __shared__ int   sidx[512];
  __shared__ float wfs[512];
  __shared__ float yfs[512];

  // column softmax (identical per-thread expression/order to r18)
  float s=0.f;
  for(int b2=0;b2<BSN;b2++) s += expf(pre[b2*NP+N]);
  float ls = logf(s);
  float wh = expf(pre[b*NP+N] - ls);

  // neff: per-half 256-tree (same order as r18's per-half block)
  red[tid] = wh*wh; __syncthreads();
  for (int s2i=128;s2i>0;s2i>>=1){ if(j<s2i) red[hf*256+j]+=red[hf*256+j+s2i]; __syncthreads(); }
  float s2 = red[hf*256]; __syncthreads();
  int doit = (1.0f/s2) < (float)(NP)/4.0f;

  float soft = 0.5f*wh + (0.5f/(float)MIDP);
  float kk = logf(soft) + gum[(b*2+hf)*256 + j];
  key[tid] = kk; __syncthreads();
  int rank = 0;
  for (int m=0;m<256;++m){ float km = key[hf*256+m]; rank += (km > kk) || (km == kk && m < j); }
  sidx[hf*256+rank] = j; __syncthreads();
  idxb[(b*2+hf)*256 + j] = sidx[hf*256+j];
  int dcol = doit ? hf*256 + sidx[hf*256+j] : N;
  yfs[N] = Y[b*NP + dcol];

  float lw = logf(wh/soft);
  red[tid] = lw; __syncthreads();
  for (int s2i=128;s2i>0;s2i>>=1){ if(j<s2i) red[hf*256+j] = fmaxf(red[hf*256+j],red[hf*256+j+s2i]); __syncthreads(); }
  float mx = red[hf*256]; __syncthreads();
  red[tid] = expf(lw-mx); __syncthreads();
  for (int s2i=128;s2i>0;s2i>>=1){ if(j<s2i) red[hf*256+j]+=red[hf*256+j+s2i]; __syncthreads(); }
  float lse = mx + logf(red[hf*256]);
  float wr = expf(lw - lse);
  float wv = doit ? wr : wh;
  wfs[N] = wv;
  out[4194336 + b*NP + N] = wv;
  if (j==0) dofl[b*2+hf] = doit;
  __syncthreads();

  // final_est: replay r18's exact 256-thread reduction sequence on LDS wf/Yf
  float v0 = 0.f;
  if (tid < 256) v0 = wfs[tid] + wfs[tid+256];
  red[tid & 255] = v0;  // only tid<256 values matter; write order safe via barrier below
  __syncthreads();
  // NOTE: the line above would race (tid and tid+256 share slot). Redo safely:
  if (tid < 256) red[tid] = wfs[tid] + wfs[tid+256];
  __syncthreads();
  for (int s2i=128;s2i>0;s2i>>=1){ if (tid < s2i) red[tid]+=red[tid+s2i]; __syncthreads(); }
  float SW = red[0]; __syncthreads();
  if (tid < 256) red[tid] = yfs[tid]*wfs[tid] + yfs[tid+256]*wfs[tid+256];
  __syncthreads();
  for (int s2i=128;s2i>0;s2i>>=1){ if (tid < s2i) red[tid]+=red[tid+s2i]; __syncthreads(); }
  float SY = red[0]; __syncthreads();
  float mu = SY/SW;
  if (tid < 256){
    float c0=yfs[tid]-mu, c1=yfs[tid+256]-mu;
    red[tid] = c0*c0 + c1*c1;
  }
  __syncthreads();
  for (int s2i=128;s2i>0;s2i>>=1){ if (tid < s2i) red[tid]+=red[tid+s2i]; __syncthreads(); }
  float SC = red[0];
  if (tid==0){
    float sig = SC/511.0f + rp[0]*rp[0];
    float a = sig + 1e-6f; float inv = 1.0f/a; float ld = logf(a);
    float inn = yv[b]-mu; float q = inn*inn*inv;
    qf[b]=q; ldb[b]=ld;
    out[b]      = mu;
    out[16 + b] = sig;
  }
}

// pf gather: 128 blocks x 256 threads, gather map cached in LDS, 64 rows/block
__global__ void k_pfg(const float* __restrict__ pr, const int* __restrict__ idxb,
                      const int* __restrict__ dofl, float* __restrict__ out){
  __shared__ int dcol[512];
  int blk = blockIdx.x;
  int q = blk & 3, lb = blk >> 2;   // lb = l*16+b
  int b = lb & 15;
  int tid = threadIdx.x;
  #pragma unroll
  for (int hf=0; hf<2; ++hf){
    int N = hf*256 + tid;
    dcol[N] = dofl[b*2+hf] ? hf*256 + idxb[(b*2+hf)*256 + tid] : N;
  }
  __syncthreads();
  int d0 = dcol[tid], d1 = dcol[tid+256];
  size_t rowbase = (size_t)lb*NH + q*64;
  for (int rr=0; rr<64; ++rr){
    size_t row = rowbase + rr;
    const float* src = pr + row*NP;
    float* dst = out + 32 + row*NP;
    dst[tid]     = src[d0];
    dst[tid+256] = src[d1];
  }
}

__global__ void k_final_scalar(const float* __restrict__ qf, const float* __restrict__ ldb,
                               float* __restrict__ out){
  if (threadIdx.x==0){
    float l=0.f, nq=0.f;
    for(int b=0;b<BSN;b++){ l += -0.5f*ldb[b]-0.5f*qf[b]; nq += qf[b]; }
    out[4202528] = l;
    out[4202529] = nq/16.0f;
  }
}

extern "C" void kernel_launch(void* const* d_in, const int* in_sizes, int n_in,
                              void* d_out, int out_size, void* d_ws, size_t ws_size,
                              hipStream_t stream) {
  const float* x      = (const float*)d_in[0];
  const float* yv     = (const float*)d_in[1];
  const float* part   = (const float*)d_in[2];
  const float* wts    = (const float*)d_in[3];
  const float* qp     = (const float*)d_in[4];
  const float* ep     = (const float*)d_in[5];
  const float* rp     = (const float*)d_in[6];
  const float* Wih0   = (const float*)d_in[7];
  const float* Whh0   = (const float*)d_in[8];
  const float* b0     = (const float*)d_in[9];
  const float* Wih1   = (const float*)d_in[10];
  const float* Whh1   = (const float*)d_in[11];
  const float* b1     = (const float*)d_in[12];
  const float* Wh     = (const float*)d_in[13];
  const float* bh     = (const float*)d_in[14];
  const float* eps_h  = (const float*)d_in[15];
  const float* eps_c  = (const float*)d_in[16];
  const float* gum    = (const float*)d_in[17];
  float* out = (float*)d_out;

  char* p = (char*)d_ws;
  f16*   W0i  = (f16*)p;  p += (size_t)GW*NH*2;
  f16*   W1c  = (f16*)p;  p += (size_t)GW*512*2;
  float* b1i  = (float*)p; p += (size_t)GW*4;
  float* xW0  = (float*)p; p += (size_t)256*GW*4;
  f16*   h0A  = (f16*)p;  p += (size_t)NCH*NH*2;
  f16*   h0B  = (f16*)p;  p += (size_t)NCH*NH*2;
  f16*   h1A  = (f16*)p;  p += (size_t)NCH*NH*2;
  f16*   h1B  = (f16*)p;  p += (size_t)NCH*NH*2;
  float* c0   = (float*)p; p += (size_t)NCH*NH*4;
  float* c1   = (float*)p; p += (size_t)NCH*NH*4;
  float* pr   = (float*)p; p += (size_t)LSN*BSN*NH*NP*4;
  float* Yb   = (float*)p; p += 32768;
  float* pre  = (float*)p; p += 32768;
  int*   idxb = (int*)p;   p += 32768;
  int*   dofl = (int*)p;   p += 128;
  float* qf   = (float*)p; p += 64;
  float* ldb  = (float*)p; p += 64;

  k_prep_all<<<1792, 256, 0, stream>>>(Whh0, Wih1, Whh1, b1, x, Wih0, b0, part,
                                       W0i, W1c, b1i, xW0, h0A, h1A, c0, c1);

  // step 0, layer 0 only (256 blocks -> z decodes to 0)
  {
    StepCfg s0{h0A, nullptr, c0, h0B, 0, 0, 0};
    k_step2<<<256, 256, 0, stream>>>(s0, s0, W0i, W1c, xW0, b1i,
        pr, eps_h, eps_c, qp, ep);
  }
  f16 *h0cur=h0B, *h0nxt=h0A, *h1cur=h1A, *h1nxt=h1B;
  for (int t=0; t<15; ++t){
    StepCfg ca{h0cur, nullptr, c0, h0nxt, 0, t+1, (t+1==15) ? 1 : 0}; // layer0 step t+1
    StepCfg cb{h0cur, h1cur,   c1, h1nxt, 1, t,   0};                 // layer1 step t
    k_step2<<<512, 256, 0, stream>>>(ca, cb, W0i, W1c, xW0, b1i,
        pr, eps_h, eps_c, qp, ep);
    f16* tmp = h0cur; h0cur = h0nxt; h0nxt = tmp;
    tmp = h1cur; h1cur = h1nxt; h1nxt = tmp;
  }
  // final: layer 1, t=15 (256 blocks, cfgA)
  {
    StepCfg fin{h0cur, h1cur, c1, h1nxt, 1, 15, 1};
    k_step2<<<256, 256, 0, stream>>>(fin, fin, W0i, W1c, xW0, b1i,
        pr, eps_h, eps_c, qp, ep);
  }

  k_obs_stats     <<<16, 512, 0, stream>>>(pr, Wh, bh, wts, yv, rp, Yb, pre);
  k_resample_final<<<16, 512, 0, stream>>>(pre, gum, Yb, yv, rp, idxb, dofl, qf, ldb, out);
  k_pfg           <<<128, 256, 0, stream>>>(pr, idxb, dofl, out);
  k_final_scalar  <<<1, 64, 0, stream>>>(qf, ldb, out);
}

// Round 20
// 388.277 us; speedup vs baseline: 1.0079x; 1.0079x over previous
//
#include <hip/hip_runtime.h>
#include <hip/hip_bf16.h>
#include <math.h>

#define LSN 2
#define BSN 16
#define NH 256
#define NP 512
#define MIDP 256
#define TTN 16
#define DIN 64
#define NCH 4096
#define GW 1024
#define PRS 268   // prstage LDS row stride (floats)
#define BUFSZ 36864  // one double-buffer slot: A[128][72] + B[128][72] f16

typedef _Float16 f16;
typedef _Float16 f16x8 __attribute__((ext_vector_type(8)));
typedef float f32x4 __attribute__((ext_vector_type(4)));

// r5-proven activation numerics (libm expf/tanhf). DO NOT replace with __expf:
// fp16-amplified activation noise flips resample argsort near-ties (r6-r8).
__device__ __forceinline__ float fsig(float x){ return 1.0f/(1.0f+expf(-x)); }

__device__ __forceinline__ float brsum512(float v, float* red){
  int tid = threadIdx.x;
  red[tid]=v; __syncthreads();
  for (int s=256; s>0; s>>=1){ if (tid<s) red[tid]+=red[tid+s]; __syncthreads(); }
  float r = red[0]; __syncthreads(); return r;
}

// gate-row remap: jhat = y*128 + q*32 + m  <->  source row = q*256 + y*32 + m
__device__ __forceinline__ int gsrow(int jp){
  return ((jp>>5)&3)*NH + (jp>>7)*32 + (jp&31);
}

// ---------- fused prep: [0,1024) weights, [1024,1280) xW0, [1280,1792) init ----------
__global__ __launch_bounds__(256) void k_prep_all(
    const float* __restrict__ Whh0, const float* __restrict__ Wih1,
    const float* __restrict__ Whh1, const float* __restrict__ b1,
    const float* __restrict__ x, const float* __restrict__ Wih0,
    const float* __restrict__ b0, const float* __restrict__ part,
    f16* __restrict__ W0i, f16* __restrict__ W1c, float* __restrict__ b1i,
    float* __restrict__ xW0,
    f16* __restrict__ h0, f16* __restrict__ h1,
    float* __restrict__ c0, float* __restrict__ c1)
{
  __shared__ float lh[64][65];
  __shared__ float lcv[64][65];
  int bid = blockIdx.x;
  int tid = threadIdx.x;
  if (bid < 1024){
    int jp = bid; int srow = gsrow(jp); int t = tid;
    W0i[(size_t)jp*NH + t]        = (f16)Whh0[(size_t)srow*NH + t];
    W1c[(size_t)jp*512 + t]       = (f16)Wih1[(size_t)srow*NH + t];
    W1c[(size_t)jp*512 + 256 + t] = (f16)Whh1[(size_t)srow*NH + t];
    if (t==0) b1i[jp] = b1[srow];
  } else if (bid < 1280){
    int row = bid - 1024; // b*16+t
    float* xr = lh[0];
    if (tid < DIN) xr[tid] = x[(size_t)row*DIN + tid];
    __syncthreads();
    int n = tid;
    for (int q=0;q<4;++q){
      int wrow = q*NH + n;
      float acc = b0[wrow];
      #pragma unroll 8
      for (int d=0; d<DIN; ++d) acc += xr[d] * Wih0[(size_t)wrow*DIN + d];
      int jhat = (n>>5)*128 + q*32 + (n&31);
      xW0[(size_t)row*GW + jhat] = acc;
    }
  } else {
    int idx = bid - 1280;          // [0,512)
    int xb = idx & 15, b = (idx>>4)&15, l = idx>>8;
    int i0 = (xb >> 2)*64, n0 = (xb & 3)*64;
    #pragma unroll
    for (int rep=0; rep<16; ++rep){
      int nn = rep*4 + (tid>>6);
      int ii = tid & 63;
      size_t rowb = ((size_t)(l*BSN + b)*NH + n0 + nn)*NP;
      lh[nn][ii]  = part[rowb + i0 + ii];
      lcv[nn][ii] = part[rowb + MIDP + i0 + ii];
    }
    __syncthreads();
    f16* h = l ? h1 : h0;
    float* c = l ? c1 : c0;
    #pragma unroll
    for (int rep=0; rep<16; ++rep){
      int ii = rep*4 + (tid>>6);
      int nn = tid & 63;
      size_t chain = (size_t)b*256 + i0 + ii;
      h[chain*NH + n0 + nn] = (f16)lh[nn][ii];
      c[chain*NH + n0 + nn] = lcv[nn][ii];
    }
  }
}

// ---------- fused step, XCD-affine 1D grid ----------
struct StepCfg {
  const f16* A1; const f16* A2;
  float* C; f16* Hout;
  int layer; int t; int is_last;
};

__global__ __launch_bounds__(256) void k_step2(
    StepCfg cfgA, StepCfg cfgB,
    const f16* __restrict__ W0i, const f16* __restrict__ W1c,
    const float* __restrict__ xw0, const float* __restrict__ b1i,
    float* __restrict__ pr, const float* __restrict__ eps_h, const float* __restrict__ eps_c,
    const float* __restrict__ qp, const float* __restrict__ ep)
{
  __shared__ __align__(16) char smem[2*BUFSZ];   // 72 KB double buffer

  const int bid = blockIdx.x;
  const int xcd = bid & 7, jj = bid >> 3;
  const int mloc = jj & 3, y = (jj >> 2) & 7, z = (jj >> 5) & 1;
  const int mt = xcd*4 + mloc;         // m-tile 0..31
  const int m0 = mt * 128;

  const StepCfg cfg = z ? cfgB : cfgA;
  const int layer  = cfg.layer;
  const int Kt     = layer ? 512 : 256;
  const int nslice = layer ? 8 : 4;
  const f16* W     = layer ? W1c : W0i;

  const int tid = threadIdx.x;
  const int lane = tid & 63, wid = tid >> 6;
  const int lr = lane >> 4, lc = lane & 15;
  const int wm = wid * 32;
  const int bb = mt >> 1;              // chain = b*256+i -> b uniform per block

  float cold[2][2][4];
  #pragma unroll
  for (int mi=0; mi<2; ++mi)
    #pragma unroll
    for (int mh=0; mh<2; ++mh)
      #pragma unroll
      for (int r=0; r<4; ++r)
        cold[mi][mh][r] = cfg.C[(size_t)(m0 + wm + mi*16 + lr*4 + r)*NH + y*32 + mh*16 + lc];

  f32x4 acc[2][8];
  #pragma unroll
  for (int mi=0;mi<2;++mi)
    #pragma unroll
    for (int ni=0;ni<8;++ni) acc[mi][ni] = (f32x4){0.f,0.f,0.f,0.f};

  const int srow = tid >> 1, sseg = (tid & 1)*32;

  float4 ra0,ra1,ra2,ra3, rb0,rb1,rb2,rb3;
  auto loadslice = [&](int ks){
    const f16* Ab; int ka;
    if (layer==1 && ks>=4){ Ab = cfg.A2; ka = (ks-4)*64; } else { Ab = cfg.A1; ka = ks*64; }
    const float4* sa = (const float4*)(Ab + (size_t)(m0+srow)*NH + ka + sseg);
    const float4* sb = (const float4*)(W + (size_t)(y*128+srow)*Kt + (size_t)ks*64 + sseg);
    ra0=sa[0]; ra1=sa[1]; ra2=sa[2]; ra3=sa[3];
    rb0=sb[0]; rb1=sb[1]; rb2=sb[2]; rb3=sb[3];
  };
  auto writeslice = [&](int buf){
    f16* base = (f16*)(smem + buf*BUFSZ);
    float4* da = (float4*)(base + srow*72 + sseg);
    da[0]=ra0; da[1]=ra1; da[2]=ra2; da[3]=ra3;
    float4* db = (float4*)(base + 128*72 + srow*72 + sseg);
    db[0]=rb0; db[1]=rb1; db[2]=rb2; db[3]=rb3;
  };

  loadslice(0);
  writeslice(0);
  __syncthreads();
  for (int ks=0; ks<nslice; ++ks){
    const int cur = ks & 1;
    const bool more = (ks+1) < nslice;
    if (more) loadslice(ks+1);
    const f16* bufA = (const f16*)(smem + cur*BUFSZ);
    const f16* bufB = bufA + 128*72;
    #pragma unroll
    for (int k2=0;k2<2;++k2){
      const int koff = k2*32 + lr*8;
      f16x8 a0 = *(const f16x8*)(bufA + (wm +  0 + lc)*72 + koff);
      f16x8 a1 = *(const f16x8*)(bufA + (wm + 16 + lc)*72 + koff);
      f16x8 b[8];
      #pragma unroll
      for (int ni=0;ni<8;++ni) b[ni] = *(const f16x8*)(bufB + (ni*16 + lc)*72 + koff);
      #pragma unroll
      for (int ni=0;ni<8;++ni){
        acc[0][ni] = __builtin_amdgcn_mfma_f32_16x16x32_f16(a0, b[ni], acc[0][ni], 0,0,0);
        acc[1][ni] = __builtin_amdgcn_mfma_f32_16x16x32_f16(a1, b[ni], acc[1][ni], 0,0,0);
      }
    }
    if (more) writeslice(cur ^ 1);
    __syncthreads();
  }

  float addv[4][2];
  {
    const float* ar = (layer==0) ? (xw0 + (size_t)(bb*TTN + cfg.t)*GW + y*128)
                                 : (b1i + y*128);
    #pragma unroll
    for (int q=0;q<4;++q)
      #pragma unroll
      for (int mh=0;mh<2;++mh)
        addv[q][mh] = ar[q*32 + mh*16 + lc];
  }

  float sq=0.f, se=0.f;
  float* prstage = (float*)smem;
  if (cfg.is_last){
    sq = sqrtf(qp[0]*qp[0]); se = sqrtf(ep[0]*ep[0]);
  }

  #pragma unroll
  for (int mi=0;mi<2;++mi)
   #pragma unroll
   for (int mh=0;mh<2;++mh)
    #pragma unroll
    for (int r=0;r<4;++r){
      float gi = acc[mi][mh+0][r] + addv[0][mh];
      float gf = acc[mi][mh+2][r] + addv[1][mh];
      float gg = acc[mi][mh+4][r] + addv[2][mh];
      float go = acc[mi][mh+6][r] + addv[3][mh];
      float c2 = fsig(gf)*cold[mi][mh][r] + fsig(gi)*tanhf(gg);
      float h2 = fsig(go)*tanhf(c2);
      int ml = wm + mi*16 + lr*4 + r;
      int chain = m0 + ml;
      int nglob = y*32 + mh*16 + lc;
      cfg.Hout[(size_t)chain*NH + nglob] = (f16)h2;
      if (!cfg.is_last){
        cfg.C[(size_t)chain*NH + nglob] = c2;
      } else {
        int ip = (mt & 1)*128 + ml;
        size_t eidx = ((size_t)(ip*LSN + layer)*BSN + bb)*NH + nglob;
        int nl = mh*16 + lc;
        prstage[nl*PRS + ml]       = h2 + sq*eps_h[eidx];
        prstage[nl*PRS + 128 + ml] = c2 + se*eps_c[eidx];
      }
    }

  if (cfg.is_last){
    __syncthreads();
    #pragma unroll
    for (int s=0;s<8;++s){
      int u = s*256 + tid;
      int nl = u >> 6, within = u & 63;
      int half = within >> 5, q4 = within & 31;
      size_t rowp = (size_t)(layer*BSN + bb)*NH + y*32 + nl;
      float4 v = *(const float4*)(prstage + nl*PRS + half*128 + q4*4);
      *(float4*)(pr + rowp*NP + half*MIDP + (mt & 1)*128 + q4*4) = v;
    }
  }
}

// ---------- post kernels ----------
__global__ void k_obs_stats(const float* __restrict__ pr, const float* __restrict__ Wh,
                            const float* __restrict__ bh, const float* __restrict__ wts,
                            const float* __restrict__ yv, const float* __restrict__ rp,
                            float* __restrict__ Y, float* __restrict__ pre){
  int b = blockIdx.x; int N = threadIdx.x;   // 512 threads
  __shared__ float red[512];
  float acc = bh[0];
  for (int n=0;n<NH;++n) acc += Wh[n] * pr[((size_t)(BSN + b)*NH + n)*NP + N];
  Y[(size_t)b*NP + N] = acc;
  float lw = logf(wts[b*NP+N]);
  float SW = brsum512(lw, red);
  float SY = brsum512(acc*lw, red);
  float mu = SY/SW;
  float cen = acc-mu;
  float SC = brsum512(cen*cen, red);
  float sig = SC/511.0f + rp[0]*rp[0];
  float a = sig+1e-6f, inv = 1.0f/a, ld = logf(a);
  float i0 = yv[b] - acc*lw/SW;
  pre[b*NP+N] = lw - 0.5f*ld - 0.5f*inv*i0*i0;
}

// resample (+ colsoftmax, per-half trees bitwise == r18) + Yf/wf in LDS + final_est
__global__ void k_resample_final(const float* __restrict__ pre, const float* __restrict__ gum,
                                 const float* __restrict__ Y, const float* __restrict__ yv,
                                 const float* __restrict__ rp,
                                 int* __restrict__ idxb, int* __restrict__ dofl,
                                 float* __restrict__ qf, float* __restrict__ ldb,
                                 float* __restrict__ out){
  int b = blockIdx.x;
  int tid = threadIdx.x;            // 0..511
  int hf = tid >> 8, j = tid & 255;
  int N = tid;                      // hf*256 + j
  __shared__ float red[512];
  __shared__ float key[512];
  __shared__ int   sidx[512];
  __shared__ float wfs[512];
  __shared__ float yfs[512];

  float s=0.f;
  for(int b2=0;b2<BSN;b2++) s += expf(pre[b2*NP+N]);
  float ls = logf(s);
  float wh = expf(pre[b*NP+N] - ls);

  red[tid] = wh*wh; __syncthreads();
  for (int s2i=128;s2i>0;s2i>>=1){ if(j<s2i) red[hf*256+j]+=red[hf*256+j+s2i]; __syncthreads(); }
  float s2 = red[hf*256]; __syncthreads();
  int doit = (1.0f/s2) < (float)(NP)/4.0f;

  float soft = 0.5f*wh + (0.5f/(float)MIDP);
  float kk = logf(soft) + gum[(b*2+hf)*256 + j];
  key[tid] = kk; __syncthreads();
  int rank = 0;
  for (int m=0;m<256;++m){ float km = key[hf*256+m]; rank += (km > kk) || (km == kk && m < j); }
  sidx[hf*256+rank] = j; __syncthreads();
  idxb[(b*2+hf)*256 + j] = sidx[hf*256+j];
  int dcol = doit ? hf*256 + sidx[hf*256+j] : N;
  yfs[N] = Y[b*NP + dcol];

  float lw = logf(wh/soft);
  red[tid] = lw; __syncthreads();
  for (int s2i=128;s2i>0;s2i>>=1){ if(j<s2i) red[hf*256+j] = fmaxf(red[hf*256+j],red[hf*256+j+s2i]); __syncthreads(); }
  float mx = red[hf*256]; __syncthreads();
  red[tid] = expf(lw-mx); __syncthreads();
  for (int s2i=128;s2i>0;s2i>>=1){ if(j<s2i) red[hf*256+j]+=red[hf*256+j+s2i]; __syncthreads(); }
  float lse = mx + logf(red[hf*256]);
  float wr = expf(lw - lse);
  float wv = doit ? wr : wh;
  wfs[N] = wv;
  out[4194336 + b*NP + N] = wv;
  if (j==0) dofl[b*2+hf] = doit;
  __syncthreads();

  // final_est: r18's exact 256-thread reduction sequence on LDS wf/Yf
  if (tid < 256) red[tid] = wfs[tid] + wfs[tid+256];
  __syncthreads();
  for (int s2i=128;s2i>0;s2i>>=1){ if (tid < s2i) red[tid]+=red[tid+s2i]; __syncthreads(); }
  float SW = red[0]; __syncthreads();
  if (tid < 256) red[tid] = yfs[tid]*wfs[tid] + yfs[tid+256]*wfs[tid+256];
  __syncthreads();
  for (int s2i=128;s2i>0;s2i>>=1){ if (tid < s2i) red[tid]+=red[tid+s2i]; __syncthreads(); }
  float SY = red[0]; __syncthreads();
  float mu = SY/SW;
  if (tid < 256){
    float c0=yfs[tid]-mu, c1=yfs[tid+256]-mu;
    red[tid] = c0*c0 + c1*c1;
  }
  __syncthreads();
  for (int s2i=128;s2i>0;s2i>>=1){ if (tid < s2i) red[tid]+=red[tid+s2i]; __syncthreads(); }
  float SC = red[0];
  if (tid==0){
    float sig = SC/511.0f + rp[0]*rp[0];
    float a = sig + 1e-6f; float inv = 1.0f/a; float ld = logf(a);
    float inn = yv[b]-mu; float q = inn*inn*inv;
    qf[b]=q; ldb[b]=ld;
    out[b]      = mu;
    out[16 + b] = sig;
  }
}

// pf gather (+ fused final scalar in block 0: qf/ldb written by previous dispatch)
__global__ void k_pfg(const float* __restrict__ pr, const int* __restrict__ idxb,
                      const int* __restrict__ dofl,
                      const float* __restrict__ qf, const float* __restrict__ ldb,
                      float* __restrict__ out){
  __shared__ int dcol[512];
  int blk = blockIdx.x;
  int q = blk & 3, lb = blk >> 2;   // lb = l*16+b
  int b = lb & 15;
  int tid = threadIdx.x;
  if (blk==0 && tid==0){
    float l=0.f, nq=0.f;
    for(int b2=0;b2<BSN;b2++){ l += -0.5f*ldb[b2]-0.5f*qf[b2]; nq += qf[b2]; }
    out[4202528] = l;
    out[4202529] = nq/16.0f;
  }
  #pragma unroll
  for (int hf=0; hf<2; ++hf){
    int N = hf*256 + tid;
    dcol[N] = dofl[b*2+hf] ? hf*256 + idxb[(b*2+hf)*256 + tid] : N;
  }
  __syncthreads();
  int d0 = dcol[tid], d1 = dcol[tid+256];
  size_t rowbase = (size_t)lb*NH + q*64;
  for (int rr=0; rr<64; ++rr){
    size_t row = rowbase + rr;
    const float* src = pr + row*NP;
    float* dst = out + 32 + row*NP;
    dst[tid]     = src[d0];
    dst[tid+256] = src[d1];
  }
}

extern "C" void kernel_launch(void* const* d_in, const int* in_sizes, int n_in,
                              void* d_out, int out_size, void* d_ws, size_t ws_size,
                              hipStream_t stream) {
  const float* x      = (const float*)d_in[0];
  const float* yv     = (const float*)d_in[1];
  const float* part   = (const float*)d_in[2];
  const float* wts    = (const float*)d_in[3];
  const float* qp     = (const float*)d_in[4];
  const float* ep     = (const float*)d_in[5];
  const float* rp     = (const float*)d_in[6];
  const float* Wih0   = (const float*)d_in[7];
  const float* Whh0   = (const float*)d_in[8];
  const float* b0     = (const float*)d_in[9];
  const float* Wih1   = (const float*)d_in[10];
  const float* Whh1   = (const float*)d_in[11];
  const float* b1     = (const float*)d_in[12];
  const float* Wh     = (const float*)d_in[13];
  const float* bh     = (const float*)d_in[14];
  const float* eps_h  = (const float*)d_in[15];
  const float* eps_c  = (const float*)d_in[16];
  const float* gum    = (const float*)d_in[17];
  float* out = (float*)d_out;

  char* p = (char*)d_ws;
  f16*   W0i  = (f16*)p;  p += (size_t)GW*NH*2;
  f16*   W1c  = (f16*)p;  p += (size_t)GW*512*2;
  float* b1i  = (float*)p; p += (size_t)GW*4;
  float* xW0  = (float*)p; p += (size_t)256*GW*4;
  f16*   h0A  = (f16*)p;  p += (size_t)NCH*NH*2;
  f16*   h0B  = (f16*)p;  p += (size_t)NCH*NH*2;
  f16*   h1A  = (f16*)p;  p += (size_t)NCH*NH*2;
  f16*   h1B  = (f16*)p;  p += (size_t)NCH*NH*2;
  float* c0   = (float*)p; p += (size_t)NCH*NH*4;
  float* c1   = (float*)p; p += (size_t)NCH*NH*4;
  float* pr   = (float*)p; p += (size_t)LSN*BSN*NH*NP*4;
  float* Yb   = (float*)p; p += 32768;
  float* pre  = (float*)p; p += 32768;
  int*   idxb = (int*)p;   p += 32768;
  int*   dofl = (int*)p;   p += 128;
  float* qf   = (float*)p; p += 64;
  float* ldb  = (float*)p; p += 64;

  k_prep_all<<<1792, 256, 0, stream>>>(Whh0, Wih1, Whh1, b1, x, Wih0, b0, part,
                                       W0i, W1c, b1i, xW0, h0A, h1A, c0, c1);

  // step 0, layer 0 only (256 blocks -> z decodes to 0)
  {
    StepCfg s0{h0A, nullptr, c0, h0B, 0, 0, 0};
    k_step2<<<256, 256, 0, stream>>>(s0, s0, W0i, W1c, xW0, b1i,
        pr, eps_h, eps_c, qp, ep);
  }
  f16 *h0cur=h0B, *h0nxt=h0A, *h1cur=h1A, *h1nxt=h1B;
  for (int t=0; t<15; ++t){
    StepCfg ca{h0cur, nullptr, c0, h0nxt, 0, t+1, (t+1==15) ? 1 : 0}; // layer0 step t+1
    StepCfg cb{h0cur, h1cur,   c1, h1nxt, 1, t,   0};                 // layer1 step t
    k_step2<<<512, 256, 0, stream>>>(ca, cb, W0i, W1c, xW0, b1i,
        pr, eps_h, eps_c, qp, ep);
    f16* tmp = h0cur; h0cur = h0nxt; h0nxt = tmp;
    tmp = h1cur; h1cur = h1nxt; h1nxt = tmp;
  }
  // final: layer 1, t=15 (256 blocks, cfgA)
  {
    StepCfg fin{h0cur, h1cur, c1, h1nxt, 1, 15, 1};
    k_step2<<<256, 256, 0, stream>>>(fin, fin, W0i, W1c, xW0, b1i,
        pr, eps_h, eps_c, qp, ep);
  }

  k_obs_stats     <<<16, 512, 0, stream>>>(pr, Wh, bh, wts, yv, rp, Yb, pre);
  k_resample_final<<<16, 512, 0, stream>>>(pre, gum, Yb, yv, rp, idxb, dofl, qf, ldb, out);
  k_pfg           <<<128, 256, 0, stream>>>(pr, idxb, dofl, qf, ldb, out);
}